// Round 11
// baseline (143.232 us; speedup 1.0000x reference)
//
#include <hip/hip_runtime.h>
#include <hip/hip_cooperative_groups.h>

namespace cg = cooperative_groups;

#define NBOX 300000
#define NFEAT 85
#define NCLS 80
#define NBUCK 4096
#define HSPLIT 16
#define CMAX 8192
#define W64 (CMAX / 64)   // 128 mask words per candidate row
#define MAXKEEP 1000
#define SC_ROWS 64
#define CB 256            // cooperative grid blocks (1 per CU)
#define CT 1024           // cooperative block threads

typedef unsigned long long u64;
typedef float f4a __attribute__((ext_vector_type(4), aligned(16)));

__device__ __forceinline__ int bucket_of(float s) {
    int b = (int)((s - 0.3f) * (4096.0f / 0.7f));
    if (b < 0) b = 0;
    if (b > NBUCK - 1) b = NBUCK - 1;
    return b;
}

__device__ __forceinline__ bool sup_iou(float by1, float bx1, float by2, float bx2, float ba,
                                        float y1, float x1, float y2, float x2, float area) {
    float iy1 = fmaxf(by1, y1), ix1 = fmaxf(bx1, x1);
    float iy2 = fminf(by2, y2), ix2 = fminf(bx2, x2);
    float inter = fmaxf(iy2 - iy1, 0.0f) * fmaxf(ix2 - ix1, 0.0f);
    float uni = ba + area - inter;
    float iou = (uni > 0.0f) ? inter / uni : 0.0f;
    return iou > 0.5f;
}

__global__ void k_init(unsigned* __restrict__ hist16, unsigned* __restrict__ cnt,
                       int* __restrict__ meta) {
    int i = blockIdx.x * blockDim.x + threadIdx.x;
    if (i < HSPLIT * NBUCK) hist16[i] = 0u;
    if (i < NBUCK) cnt[i] = 0u;
    if (i < 48) meta[i] = 0;
}

// Coalesced staged scores + 16-way split histograms (unchanged from R8/R10).
__global__ void __launch_bounds__(256) k_scores(const float* __restrict__ in,
        float* __restrict__ scores, unsigned* __restrict__ hist16) {
    __shared__ float lds[SC_ROWS * NFEAT];  // 21760 B
    int t = threadIdx.x;
    long long rbase = (long long)blockIdx.x * SC_ROWS;
    int rows = (NBOX - rbase < SC_ROWS) ? (int)(NBOX - rbase) : SC_ROWS;
    int nfl = rows * NFEAT;
    int nf4 = nfl >> 2;
    const f4a* src = (const f4a*)(in + rbase * NFEAT);
    f4a* dst = (f4a*)lds;
    for (int k = t; k < nf4; k += 256) dst[k] = src[k];
    for (int k = (nf4 << 2) + t; k < nfl; k += 256) lds[k] = in[rbase * NFEAT + k];
    __syncthreads();
    unsigned* myhist = hist16 + (size_t)(blockIdx.x & (HSPLIT - 1)) * NBUCK;
    int row = t >> 2, part = t & 3;
    if (row < rows) {
        const float* r = lds + row * NFEAT;
        const float* p = r + 5 + 20 * part;
        float mx = p[0];
        #pragma unroll
        for (int j = 1; j < 20; ++j) mx = fmaxf(mx, p[j]);
        mx = fmaxf(mx, __shfl_xor(mx, 1));
        mx = fmaxf(mx, __shfl_xor(mx, 2));
        if (part == 0) {
            float best = r[4] * mx;
            scores[rbase + row] = best;
            if (best >= 0.3f) atomicAdd(&myhist[bucket_of(best)], 1u);
        }
    }
}

// ---------------- phase functions (shared by coop kernel and fallback) -------
// meta line layout (64B-separated by writer phase, volatile-read by consumers):
//   meta[0]=total, meta[1]=bstar   (thresh)
//   meta[16]=nvalid                (vscan)
//   meta[32]=kept count            (sweepfin)

__device__ void phase_thresh(const unsigned* __restrict__ hist16,
        unsigned* __restrict__ histsum, unsigned* __restrict__ off,
        int* __restrict__ meta, unsigned* scan, int t) {
    unsigned h[4];
    unsigned s = 0;
    #pragma unroll
    for (int j = 0; j < 4; ++j) {
        unsigned v = 0;
        for (int g = 0; g < HSPLIT; ++g) v += hist16[g * NBUCK + t * 4 + j];
        h[j] = v; histsum[t * 4 + j] = v; s += v;
    }
    scan[t] = s;
    __syncthreads();
    for (int o = 1; o < 1024; o <<= 1) {
        unsigned add = (t + o < 1024) ? scan[t + o] : 0u;
        __syncthreads();
        scan[t] += add;
        __syncthreads();
    }
    unsigned after = (t + 1 < 1024) ? scan[t + 1] : 0u;
    unsigned suf[5];
    suf[4] = after;
    #pragma unroll
    for (int j = 3; j >= 0; --j) suf[j] = suf[j + 1] + h[j];
    #pragma unroll
    for (int j = 0; j < 4; ++j) {
        int b = t * 4 + j;
        off[b] = suf[j] - h[j];
        unsigned sufb = suf[j], sufprev;
        if (b == 0) sufprev = 0xFFFFFFFFu;
        else if (j > 0) sufprev = suf[j - 1];
        else {
            unsigned hprev = 0;
            for (int g = 0; g < HSPLIT; ++g) hprev += hist16[g * NBUCK + b - 1];
            sufprev = sufb + hprev;
        }
        if (sufb <= (unsigned)CMAX && sufprev > (unsigned)CMAX) {
            meta[1] = b;
            meta[0] = (int)sufb;
        }
    }
}

__device__ void phase_scatter(const float* __restrict__ scores, const int* meta,
        const unsigned* __restrict__ off, unsigned* __restrict__ cnt,
        u64* __restrict__ unsorted, int gtid, int gstride) {
    int bstar = ((volatile const int*)meta)[1];
    for (int i = gtid; i < NBOX; i += gstride) {
        float s = scores[i];
        if (s < 0.3f) continue;
        int b = bucket_of(s);
        if (b < bstar) continue;
        unsigned slot = off[b] + atomicAdd(&cnt[b], 1u);
        if (slot < CMAX)
            unsorted[slot] = ((u64)__float_as_uint(s) << 32) |
                             (u64)(0xFFFFFFFFu - (unsigned)i);
    }
}

__device__ void phase_rank(const float* __restrict__ in, const u64* __restrict__ unsorted,
        const unsigned* __restrict__ off, const unsigned* __restrict__ histsum,
        const int* meta, u64* __restrict__ sorted, float4* __restrict__ boxes4,
        unsigned* __restrict__ vflag, int gtid) {
    int total = ((volatile const int*)meta)[0];
    int i = gtid;
    if (i >= total) return;
    u64 k = unsorted[i];
    float s = __uint_as_float((unsigned)(k >> 32));
    int b = bucket_of(s);
    unsigned base = off[b], n = histsum[b], r = 0;
    for (unsigned u = 0; u < n; ++u) r += (unsorted[base + u] > k) ? 1u : 0u;
    int bi = (int)(0xFFFFFFFFu - (unsigned)(k & 0xFFFFFFFFull));
    const float* p = in + (size_t)bi * NFEAT;
    float4 bx = make_float4(p[0], p[1], p[2], p[3]);  // y1,x1,y2,x2
    sorted[base + r] = k;
    boxes4[base + r] = bx;
    vflag[base + r] = (bx.z > bx.x && bx.w > bx.y) ? 1u : 0u;
}

__device__ void phase_vscan(const unsigned* __restrict__ vflag,
        const float4* __restrict__ boxes4, int* meta, unsigned* __restrict__ vincl,
        unsigned* __restrict__ cmap, float4* __restrict__ cboxes,
        unsigned* scan, int t) {
    int total = ((volatile int*)meta)[0];
    unsigned f[8];
    unsigned run = 0;
    #pragma unroll
    for (int e = 0; e < 8; ++e) {
        int s = t * 8 + e;
        unsigned v = (s < total) ? vflag[s] : 0u;
        run += v; f[e] = run;
    }
    scan[t] = run;
    __syncthreads();
    for (int o = 1; o < 1024; o <<= 1) {
        unsigned add = (t >= o) ? scan[t - o] : 0u;
        __syncthreads();
        scan[t] += add;
        __syncthreads();
    }
    unsigned excl = (t > 0) ? scan[t - 1] : 0u;
    #pragma unroll
    for (int e = 0; e < 8; ++e) {
        int s = t * 8 + e;
        unsigned incl = excl + f[e];
        vincl[s] = incl;
        if (s < total && vflag[s]) {
            cmap[incl - 1] = (unsigned)s;
            cboxes[incl - 1] = boxes4[s];
        }
    }
    if (t == 1023) meta[16] = (int)scan[1023];
}

// One tile per wave (grid-stride over upper-triangle tiles); lane l is column
// tj*64+l; row boxes broadcast via shfl; lane r keeps row ti*64+r's word.
__device__ void phase_masks(const float4* __restrict__ cboxes, const int* meta,
        u64* __restrict__ masks, int gwave, int nwaves, int lane) {
    int nv = ((volatile const int*)meta)[16];
    int nblk = (nv + 63) >> 6;
    int T = nblk * (nblk + 1) / 2;
    for (int tile = gwave; tile < T; tile += nwaves) {
        int ti = 0, rem = tile, rowlen = nblk;
        while (rem >= rowlen) { rem -= rowlen; --rowlen; ++ti; }
        int tj = ti + rem;
        int ri = ti * 64 + lane;
        int cj = tj * 64 + lane;
        float4 rb = (ri < nv) ? cboxes[ri] : make_float4(0.f, 0.f, 0.f, 0.f);
        bool cvalid = (cj < nv);
        float4 cb = cvalid ? cboxes[cj] : make_float4(0.f, 0.f, 0.f, 0.f);
        float carea = (cb.z - cb.x) * (cb.w - cb.y);
        u64 myw = 0ull;
        for (int r = 0; r < 64; ++r) {
            int i = ti * 64 + r;
            float by1 = __shfl(rb.x, r), bx1 = __shfl(rb.y, r);
            float by2 = __shfl(rb.z, r), bx2 = __shfl(rb.w, r);
            float ba = (by2 - by1) * (bx2 - bx1);
            bool s = cvalid && (cj > i) && (i < nv) &&
                     sup_iou(by1, bx1, by2, bx2, ba, cb.x, cb.y, cb.z, cb.w, carea);
            u64 word = __ballot(s ? 1 : 0);
            if (lane == r) myw = word;
        }
        if (ri < nv) masks[(size_t)ri * W64 + tj] = myw;
    }
}

// Sweep (wave 0): plain global loads only — no LDS staging, nothing for the
// compiler to vmcnt(0)-drain. Kept rows (~16-50/block) loaded 4-wide ILP after
// the chain; next diag prefetched early. Then finalize scan (1024 threads).
__device__ void phase_sweepfin(const u64* __restrict__ masks,
        const unsigned* __restrict__ cmap, const unsigned* __restrict__ vincl,
        const unsigned* __restrict__ vflag, int* meta, int* __restrict__ kfinal,
        unsigned* scan, u64* vkeptw, int* sh_wlim, int t) {
    if (t < W64) vkeptw[t] = 0ull;
    if (t == 0) *sh_wlim = 0;
    __syncthreads();
    int total = ((volatile int*)meta)[0];
    int nv = ((volatile int*)meta)[16];
    if (t < 64) {
        int lane = t;
        int nblkv = (nv + 63) >> 6;
        u64 r0 = 0ull, r1 = 0ull;
        int nkv = 0, wl = 0;
        u64 diag_cur = (nblkv > 0) ? masks[(size_t)lane * W64] : 0ull;
        for (int w = 0; w < nblkv; ++w) {
            int base = w << 6;
            int rc = nv - base;
            u64 vm = (rc >= 64) ? ~0ull : ((1ull << rc) - 1ull);
            u64 rw = __shfl((w & 1) ? r1 : r0, w >> 1);
            u64 surv = ~rw & vm;
            int cend = (base + 63 < nv - 1) ? (base + 63) : (nv - 1);
            unsigned cm = cmap[cend];
            u64 diag_next = (w + 1 < nblkv)
                ? masks[(size_t)((w + 1) * 64 + lane) * W64 + (w + 1)] : 0ull;
            // in-block greedy chain (nonzero-diag candidates only)
            u64 Z = __ballot(diag_cur == 0ull);
            u64 rem = 0ull;
            u64 mnz = surv & ~Z;
            while (mnz) {
                int bb = __ffsll(mnz) - 1;
                mnz &= mnz - 1;
                if ((rem >> bb) & 1ull) continue;
                u64 db = __shfl(diag_cur, bb);
                rem |= db;
                mnz &= ~db;
            }
            u64 kept = surv & ~rem;
            int kp = __popcll(kept);
            // R-update: direct loads of kept rows, 4 independent rows in flight
            u64 km = kept, alo = 0ull, ahi = 0ull;
            while (km) {
                int b0 = __ffsll(km) - 1; km &= km - 1;
                const u64* p0 = masks + (size_t)(base + b0) * W64 + 2 * lane;
                u64 l0 = p0[0], h0 = p0[1];
                u64 l1 = 0, h1 = 0, l2 = 0, h2 = 0, l3 = 0, h3 = 0;
                if (km) { int b = __ffsll(km) - 1; km &= km - 1;
                    const u64* p = masks + (size_t)(base + b) * W64 + 2 * lane;
                    l1 = p[0]; h1 = p[1]; }
                if (km) { int b = __ffsll(km) - 1; km &= km - 1;
                    const u64* p = masks + (size_t)(base + b) * W64 + 2 * lane;
                    l2 = p[0]; h2 = p[1]; }
                if (km) { int b = __ffsll(km) - 1; km &= km - 1;
                    const u64* p = masks + (size_t)(base + b) * W64 + 2 * lane;
                    l3 = p[0]; h3 = p[1]; }
                alo |= l0 | l1 | l2 | l3;
                ahi |= h0 | h1 | h2 | h3;
            }
            r0 |= alo; r1 |= ahi;
            if (lane == 0) vkeptw[w] = kept;
            nkv += kp;
            wl = w + 1;
            if ((int)cm - cend + nkv >= MAXKEEP) break;  // merged kept reached cap
            diag_cur = diag_next;
        }
        if (lane == 0) *sh_wlim = wl;
    }
    __syncthreads();
    int wlim = *sh_wlim;
    // finalize: kept(s) = invalid(s) OR valid-kept(s); first MAXKEEP in order
    unsigned f[8];
    unsigned run = 0;
    #pragma unroll
    for (int e = 0; e < 8; ++e) {
        int s = t * 8 + e;
        unsigned kept = 0u;
        if (s < total) {
            if (!vflag[s]) kept = 1u;
            else {
                unsigned c = vincl[s] - 1u;
                int w = (int)(c >> 6);
                if (w < wlim && ((vkeptw[w] >> (c & 63u)) & 1ull)) kept = 1u;
            }
        }
        run += kept; f[e] = run;
    }
    scan[t] = run;
    __syncthreads();
    for (int o = 1; o < 1024; o <<= 1) {
        unsigned add = (t >= o) ? scan[t - o] : 0u;
        __syncthreads();
        scan[t] += add;
        __syncthreads();
    }
    unsigned excl = (t > 0) ? scan[t - 1] : 0u;
    #pragma unroll
    for (int e = 0; e < 8; ++e) {
        int s = t * 8 + e;
        unsigned kept = 0u;
        if (s < total) {
            if (!vflag[s]) kept = 1u;
            else {
                unsigned c = vincl[s] - 1u;
                int w = (int)(c >> 6);
                if (w < wlim && ((vkeptw[w] >> (c & 63u)) & 1ull)) kept = 1u;
            }
        }
        unsigned incl = excl + f[e];
        if (kept && incl <= (unsigned)MAXKEEP) kfinal[incl - 1] = s;
    }
    if (t == 1023) {
        unsigned tot = scan[1023];
        meta[32] = (int)(tot < (unsigned)MAXKEEP ? tot : (unsigned)MAXKEEP);
    }
}

__device__ void phase_output(const float* __restrict__ in, const u64* __restrict__ sorted,
        const int* meta, const int* __restrict__ kfinal, float* __restrict__ out,
        int gwave, int lane) {
    if (gwave >= MAXKEEP) return;
    int kc = ((volatile const int*)meta)[32];
    if (gwave < kc) {
        int pos = kfinal[gwave];
        u64 key = sorted[pos];
        int bi = (int)(0xFFFFFFFFu - (unsigned)(key & 0xFFFFFFFFull));
        const float* row = in + (size_t)bi * NFEAT;
        float conf = row[4];
        float v0 = (lane < NCLS) ? conf * row[5 + lane] : -1.0f;
        float v1 = (lane < NCLS - 64) ? conf * row[5 + 64 + lane] : -1.0f;
        float bv = (v1 > v0) ? v1 : v0;          // tie -> v0 (smaller idx)
        int bix = (v1 > v0) ? (64 + lane) : lane;
        #pragma unroll
        for (int o = 1; o < 64; o <<= 1) {
            float ov = __shfl_xor(bv, o);
            int oi = __shfl_xor(bix, o);
            if (ov > bv || (ov == bv && oi < bix)) { bv = ov; bix = oi; }
        }
        float wv = 0.f;
        if (lane < 4) wv = row[lane];
        else if (lane == 4) wv = (float)bix;
        else wv = bv;
        if (lane < 6) out[gwave * 6 + lane] = wv;
    } else {
        if (lane < 6) out[gwave * 6 + lane] = 0.f;
    }
}

// ---------------- cooperative fused tail --------------------------------------
__global__ void __launch_bounds__(CT) k_coop(const float* in, float* scores,
        unsigned* hist16, unsigned* histsum, unsigned* off, unsigned* cnt,
        u64* unsorted, u64* sorted, float4* boxes4, unsigned* vflag,
        unsigned* vincl, unsigned* cmap, float4* cboxes, u64* masks,
        int* meta, int* kfinal, float* out) {
    cg::grid_group grid = cg::this_grid();
    __shared__ unsigned scan[1024];
    __shared__ u64 vkeptw[W64];
    __shared__ int sh_wlim;
    int t = threadIdx.x, b = blockIdx.x;
    int gtid = b * CT + t;
    int lane = t & 63;
    int gwave = gtid >> 6;
    if (b == 0) phase_thresh(hist16, histsum, off, meta, scan, t);
    grid.sync();
    phase_scatter(scores, meta, off, cnt, unsorted, gtid, CB * CT);
    grid.sync();
    phase_rank(in, unsorted, off, histsum, meta, sorted, boxes4, vflag, gtid);
    grid.sync();
    if (b == 0) phase_vscan(vflag, boxes4, meta, vincl, cmap, cboxes, scan, t);
    grid.sync();
    phase_masks(cboxes, meta, masks, gwave, CB * 16, lane);
    grid.sync();
    if (b == 0) phase_sweepfin(masks, cmap, vincl, vflag, meta, kfinal, scan, vkeptw, &sh_wlim, t);
    grid.sync();
    phase_output(in, sorted, meta, kfinal, out, gwave, lane);
}

// ---------------- fallback wrappers (same phases, separate launches) ----------
__global__ void __launch_bounds__(1024) k_thresh_s(const unsigned* hist16,
        unsigned* histsum, unsigned* off, int* meta) {
    __shared__ unsigned scan[1024];
    phase_thresh(hist16, histsum, off, meta, scan, threadIdx.x);
}
__global__ void k_scatter_s(const float* scores, const int* meta, const unsigned* off,
        unsigned* cnt, u64* unsorted) {
    phase_scatter(scores, meta, off, cnt, unsorted,
                  blockIdx.x * 256 + threadIdx.x, 1172 * 256);
}
__global__ void k_rank_s(const float* in, const u64* unsorted, const unsigned* off,
        const unsigned* histsum, const int* meta, u64* sorted, float4* boxes4,
        unsigned* vflag) {
    phase_rank(in, unsorted, off, histsum, meta, sorted, boxes4, vflag,
               blockIdx.x * 256 + threadIdx.x);
}
__global__ void __launch_bounds__(1024) k_vscan_s(const unsigned* vflag,
        const float4* boxes4, int* meta, unsigned* vincl, unsigned* cmap,
        float4* cboxes) {
    __shared__ unsigned scan[1024];
    phase_vscan(vflag, boxes4, meta, vincl, cmap, cboxes, scan, threadIdx.x);
}
__global__ void __launch_bounds__(1024) k_masks_s(const float4* cboxes,
        const int* meta, u64* masks) {
    int gwave = blockIdx.x * 16 + (threadIdx.x >> 6);
    phase_masks(cboxes, meta, masks, gwave, 64 * 16, threadIdx.x & 63);
}
__global__ void __launch_bounds__(1024) k_sweepfin_s(const u64* masks,
        const unsigned* cmap, const unsigned* vincl, const unsigned* vflag,
        int* meta, int* kfinal) {
    __shared__ unsigned scan[1024];
    __shared__ u64 vkeptw[W64];
    __shared__ int sh_wlim;
    phase_sweepfin(masks, cmap, vincl, vflag, meta, kfinal, scan, vkeptw,
                   &sh_wlim, threadIdx.x);
}
__global__ void __launch_bounds__(1024) k_output_s(const float* in, const u64* sorted,
        const int* meta, const int* kfinal, float* out) {
    int gwave = blockIdx.x * 16 + (threadIdx.x >> 6);
    phase_output(in, sorted, meta, kfinal, out, gwave, threadIdx.x & 63);
}

extern "C" void kernel_launch(void* const* d_in, const int* in_sizes, int n_in,
                              void* d_out, int out_size, void* d_ws, size_t ws_size,
                              hipStream_t stream) {
    const float* in = (const float*)d_in[0];
    float* out = (float*)d_out;
    char* ws = (char*)d_ws;
    // ws layout (bytes). masks OVERLAYS sort-phase scratch (dead before masks phase).
    //   [0, 65536)           sorted   u64[8192]
    //   [65536, 65728)       meta     i32[48] (writer-phase fields on separate 64B lines)
    //   [65728, 69824)       kfinal   i32[1024]
    //   [69824, 102592)      vflag    u32[8192]
    //   [102592, 135360)     vincl    u32[8192]
    //   [135360, 168128)     cmap     u32[8192]
    //   [168128, 299200)     cboxes   float4[8192]
    //   [299200, 430272)     boxes4   float4[8192]
    //   [430272, 8818880)    masks    u64[8192*128] (8 MB), overlaying:
    //     [430272, 1630272)    scores   f32[300000]
    //     [1630272, 1892416)   hist16   u32[16*4096]
    //     [1892416, 1908800)   histsum  u32[4096]
    //     [1908800, 1925184)   cnt      u32[4096]
    //     [1925184, 1941568)   off      u32[4096]
    //     [1941568, 2007104)   unsorted u64[8192]
    u64* sorted = (u64*)(ws);
    int* meta = (int*)(ws + 65536);
    int* kfinal = (int*)(ws + 65728);
    unsigned* vflag = (unsigned*)(ws + 69824);
    unsigned* vincl = (unsigned*)(ws + 102592);
    unsigned* cmap = (unsigned*)(ws + 135360);
    float4* cboxes = (float4*)(ws + 168128);
    float4* boxes4 = (float4*)(ws + 299200);
    u64* masks = (u64*)(ws + 430272);
    float* scores = (float*)(ws + 430272);
    unsigned* hist16 = (unsigned*)(ws + 1630272);
    unsigned* histsum = (unsigned*)(ws + 1892416);
    unsigned* cnt = (unsigned*)(ws + 1908800);
    unsigned* off = (unsigned*)(ws + 1925184);
    u64* unsorted = (u64*)(ws + 1941568);

    k_init<<<dim3(256), dim3(256), 0, stream>>>(hist16, cnt, meta);
    k_scores<<<dim3((NBOX + SC_ROWS - 1) / SC_ROWS), dim3(256), 0, stream>>>(in, scores, hist16);

    int dev = 0;
    (void)hipGetDevice(&dev);
    int coopAttr = 0;
    (void)hipDeviceGetAttribute(&coopAttr, hipDeviceAttributeCooperativeLaunch, dev);
    int maxb = 0;
    hipError_t occErr = hipOccupancyMaxActiveBlocksPerMultiprocessor(&maxb, k_coop, CT, 0);
    bool useCoop = (coopAttr != 0) && (occErr == hipSuccess) && (maxb >= 1);
    if (useCoop) {
        void* kp[17] = { (void*)&in, (void*)&scores, (void*)&hist16, (void*)&histsum,
                         (void*)&off, (void*)&cnt, (void*)&unsorted, (void*)&sorted,
                         (void*)&boxes4, (void*)&vflag, (void*)&vincl, (void*)&cmap,
                         (void*)&cboxes, (void*)&masks, (void*)&meta, (void*)&kfinal,
                         (void*)&out };
        hipError_t e = hipLaunchCooperativeKernel((const void*)k_coop,
                dim3(CB), dim3(CT), kp, 0, stream);
        if (e != hipSuccess) useCoop = false;
    }
    if (!useCoop) {
        k_thresh_s<<<dim3(1), dim3(1024), 0, stream>>>(hist16, histsum, off, meta);
        k_scatter_s<<<dim3(1172), dim3(256), 0, stream>>>(scores, meta, off, cnt, unsorted);
        k_rank_s<<<dim3(32), dim3(256), 0, stream>>>(in, unsorted, off, histsum, meta, sorted, boxes4, vflag);
        k_vscan_s<<<dim3(1), dim3(1024), 0, stream>>>(vflag, boxes4, meta, vincl, cmap, cboxes);
        k_masks_s<<<dim3(64), dim3(1024), 0, stream>>>(cboxes, meta, masks);
        k_sweepfin_s<<<dim3(1), dim3(1024), 0, stream>>>(masks, cmap, vincl, vflag, meta, kfinal);
        k_output_s<<<dim3(63), dim3(1024), 0, stream>>>(in, sorted, meta, kfinal, out);
    }
}

// Round 12
// 134.310 us; speedup vs baseline: 1.0664x; 1.0664x over previous
//
#include <hip/hip_runtime.h>

#define NBOX 300000
#define NFEAT 85
#define NCLS 80
#define NBUCK 4096
#define HSPLIT 16
#define CMAX 8192
#define W64 (CMAX / 64)   // 128 mask words per candidate row
#define MAXKEEP 1000
#define SC_ROWS 64        // k_scores tile rows

typedef unsigned long long u64;
typedef float f4a __attribute__((ext_vector_type(4), aligned(16)));

__device__ __forceinline__ int bucket_of(float s) {
    int b = (int)((s - 0.3f) * (4096.0f / 0.7f));
    if (b < 0) b = 0;
    if (b > NBUCK - 1) b = NBUCK - 1;
    return b;
}

__device__ __forceinline__ bool sup_iou(float by1, float bx1, float by2, float bx2, float ba,
                                        float y1, float x1, float y2, float x2, float area) {
    float iy1 = fmaxf(by1, y1), ix1 = fmaxf(bx1, x1);
    float iy2 = fminf(by2, y2), ix2 = fminf(bx2, x2);
    float inter = fmaxf(iy2 - iy1, 0.0f) * fmaxf(ix2 - ix1, 0.0f);
    float uni = ba + area - inter;
    float iou = (uni > 0.0f) ? inter / uni : 0.0f;
    return iou > 0.5f;
}

__global__ void k_init(unsigned* __restrict__ hist16, unsigned* __restrict__ cnt,
                       int* __restrict__ meta) {
    int i = blockIdx.x * blockDim.x + threadIdx.x;
    if (i < HSPLIT * NBUCK) hist16[i] = 0u;
    if (i < NBUCK) cnt[i] = 0u;
    if (i < 16) meta[i] = 0;
}

// Coalesced staged scores + 16-way split histograms (R8/R10 structure, proven).
// conf*max(p) == max(conf*p) exactly (conf>=0, RN monotone).
__global__ void __launch_bounds__(256) k_scores(const float* __restrict__ in,
        float* __restrict__ scores, unsigned* __restrict__ hist16) {
    __shared__ float lds[SC_ROWS * NFEAT];  // 21760 B
    int t = threadIdx.x;
    long long rbase = (long long)blockIdx.x * SC_ROWS;
    int rows = (NBOX - rbase < SC_ROWS) ? (int)(NBOX - rbase) : SC_ROWS;
    int nfl = rows * NFEAT;
    int nf4 = nfl >> 2;
    const f4a* src = (const f4a*)(in + rbase * NFEAT);
    f4a* dst = (f4a*)lds;
    for (int k = t; k < nf4; k += 256) dst[k] = src[k];
    for (int k = (nf4 << 2) + t; k < nfl; k += 256) lds[k] = in[rbase * NFEAT + k];
    __syncthreads();
    unsigned* myhist = hist16 + (size_t)(blockIdx.x & (HSPLIT - 1)) * NBUCK;
    int row = t >> 2, part = t & 3;
    if (row < rows) {
        const float* r = lds + row * NFEAT;
        const float* p = r + 5 + 20 * part;
        float mx = p[0];
        #pragma unroll
        for (int j = 1; j < 20; ++j) mx = fmaxf(mx, p[j]);
        mx = fmaxf(mx, __shfl_xor(mx, 1));
        mx = fmaxf(mx, __shfl_xor(mx, 2));
        if (part == 0) {
            float best = r[4] * mx;
            scores[rbase + row] = best;
            if (best >= 0.3f) atomicAdd(&myhist[bucket_of(best)], 1u);
        }
    }
}

// Sum split hists; suffix sums; bstar = smallest b with suffix(b) <= CMAX;
// off[b] = suffix(b+1); histsum[b] = bucket size; meta[0]=count, meta[1]=bstar.
__global__ void __launch_bounds__(1024) k_thresh(const unsigned* __restrict__ hist16,
        unsigned* __restrict__ histsum, unsigned* __restrict__ off, int* __restrict__ meta) {
    __shared__ unsigned chunk[1024];
    int t = threadIdx.x;
    unsigned h[4];
    unsigned s = 0;
    #pragma unroll
    for (int j = 0; j < 4; ++j) {
        unsigned v = 0;
        for (int g = 0; g < HSPLIT; ++g) v += hist16[g * NBUCK + t * 4 + j];
        h[j] = v; histsum[t * 4 + j] = v; s += v;
    }
    chunk[t] = s;
    __syncthreads();
    for (int o = 1; o < 1024; o <<= 1) {
        unsigned add = (t + o < 1024) ? chunk[t + o] : 0u;
        __syncthreads();
        chunk[t] += add;
        __syncthreads();
    }
    unsigned after = (t + 1 < 1024) ? chunk[t + 1] : 0u;
    unsigned suf[5];
    suf[4] = after;
    #pragma unroll
    for (int j = 3; j >= 0; --j) suf[j] = suf[j + 1] + h[j];
    #pragma unroll
    for (int j = 0; j < 4; ++j) {
        int b = t * 4 + j;
        off[b] = suf[j] - h[j];
        unsigned sufb = suf[j], sufprev;
        if (b == 0) sufprev = 0xFFFFFFFFu;
        else if (j > 0) sufprev = suf[j - 1];
        else {
            unsigned hprev = 0;
            for (int g = 0; g < HSPLIT; ++g) hprev += hist16[g * NBUCK + b - 1];
            sufprev = sufb + hprev;
        }
        if (sufb <= (unsigned)CMAX && sufprev > (unsigned)CMAX) {
            meta[1] = b;
            meta[0] = (int)sufb;
        }
    }
}

__global__ void k_scatter(const float* __restrict__ scores, const int* __restrict__ meta,
                          const unsigned* __restrict__ off, unsigned* __restrict__ cnt,
                          u64* __restrict__ unsorted) {
    int i = blockIdx.x * blockDim.x + threadIdx.x;
    if (i >= NBOX) return;
    float s = scores[i];
    if (s < 0.3f) return;
    int b = bucket_of(s);
    if (b < meta[1]) return;
    unsigned slot = off[b] + atomicAdd(&cnt[b], 1u);
    if (slot < CMAX)
        unsorted[slot] = ((u64)__float_as_uint(s) << 32) |
                         (u64)(0xFFFFFFFFu - (unsigned)i);
}

// Exact rank within bucket -> fully sorted, deterministic. Also compacts the box
// into boxes4 and emits vflag (both extents strictly positive).
__global__ void k_rank(const float* __restrict__ in, const u64* __restrict__ unsorted,
                       const unsigned* __restrict__ off, const unsigned* __restrict__ histsum,
                       const int* __restrict__ meta, u64* __restrict__ sorted,
                       float4* __restrict__ boxes4, unsigned* __restrict__ vflag) {
    int i = blockIdx.x * blockDim.x + threadIdx.x;
    int total = meta[0];
    if (i >= total) return;
    u64 k = unsorted[i];
    float s = __uint_as_float((unsigned)(k >> 32));
    int b = bucket_of(s);
    unsigned base = off[b];
    unsigned n = histsum[b];
    unsigned r = 0;
    for (unsigned u = 0; u < n; ++u) r += (unsorted[base + u] > k) ? 1u : 0u;
    int bi = (int)(0xFFFFFFFFu - (unsigned)(k & 0xFFFFFFFFull));
    const float* p = in + (size_t)bi * NFEAT;
    float4 bx = make_float4(p[0], p[1], p[2], p[3]);  // y1,x1,y2,x2
    sorted[base + r] = k;
    boxes4[base + r] = bx;
    vflag[base + r] = (bx.z > bx.x && bx.w > bx.y) ? 1u : 0u;
}

// Prefix-scan valid flags; build compact map + compact boxes; meta[3] = nvalid.
// Degenerate boxes have IoU==0 with everything: never suppress, never suppressed
// -> excluded from masks/sweep, always kept.
__global__ void __launch_bounds__(1024) k_vscan(const unsigned* __restrict__ vflag,
        const float4* __restrict__ boxes4, int* __restrict__ meta,
        unsigned* __restrict__ vincl, unsigned* __restrict__ cmap,
        float4* __restrict__ cboxes) {
    __shared__ unsigned ps[1024];
    int t = threadIdx.x;
    int total = meta[0];
    unsigned f[8];
    unsigned run = 0;
    #pragma unroll
    for (int e = 0; e < 8; ++e) {
        int s = t * 8 + e;
        unsigned v = (s < total) ? vflag[s] : 0u;
        run += v;
        f[e] = run;
    }
    ps[t] = run;
    __syncthreads();
    for (int o = 1; o < 1024; o <<= 1) {
        unsigned add = (t >= o) ? ps[t - o] : 0u;
        __syncthreads();
        ps[t] += add;
        __syncthreads();
    }
    unsigned excl = (t > 0) ? ps[t - 1] : 0u;
    #pragma unroll
    for (int e = 0; e < 8; ++e) {
        int s = t * 8 + e;
        unsigned incl = excl + f[e];
        vincl[s] = incl;
        if (s < total && vflag[s]) {
            cmap[incl - 1] = (unsigned)s;
            cboxes[incl - 1] = boxes4[s];
        }
    }
    if (t == 1023) meta[3] = (int)ps[1023];
}

// Pairwise masks over COMPACT valid candidates (R10 structure: 4 waves x 16
// ballot-rows per 64x64 tile). masks[i][w] bit b = (j=w*64+b) > i && IoU>0.5.
// Words tj >= ti written; sub-diagonal garbage never effectively read.
__global__ void __launch_bounds__(256) k_masks(const float4* __restrict__ cboxes,
        const int* __restrict__ meta, u64* __restrict__ masks) {
    int ti = blockIdx.y, tj = blockIdx.x;
    if (tj < ti) return;
    int count = meta[3];
    if (ti * 64 >= count) return;
    __shared__ float4 rb[64];
    int t = threadIdx.x;
    if (t < 64) {
        int r = ti * 64 + t;
        rb[t] = (r < count) ? cboxes[r] : make_float4(0.f, 0.f, 0.f, 0.f);
    }
    int lane = t & 63, wid = t >> 6;
    int cj = tj * 64 + lane;
    bool cvalid = (cj < count);
    float4 cb = cvalid ? cboxes[cj] : make_float4(0.f, 0.f, 0.f, 0.f);
    float carea = (cb.z - cb.x) * (cb.w - cb.y);
    __syncthreads();
    #pragma unroll
    for (int r = 0; r < 16; ++r) {
        int i = ti * 64 + wid * 16 + r;
        float4 b = rb[wid * 16 + r];
        float ba = (b.z - b.x) * (b.w - b.y);
        bool s = cvalid && (cj > i) && (i < count) &&
                 sup_iou(b.x, b.y, b.z, b.w, ba, cb.x, cb.y, cb.z, cb.w, carea);
        u64 word = __ballot(s ? 1 : 0);
        if (lane == 0) masks[(size_t)i * W64 + tj] = word;
    }
}

// Sweep-v3 (validated inside R11's coop kernel): wave 0 does the greedy sweep
// with PLAIN global loads only — no LDS staging, nothing for the compiler to
// vmcnt(0)-drain. Kept rows (~16-50/block) loaded 4-wide ILP after the chain;
// next block's diag word prefetched early. Then all 1024 threads: finalize
// scan (kept(s) = invalid(s) OR valid-kept(s); first MAXKEEP in slot order).
__global__ void __launch_bounds__(1024) k_sweepfin(const u64* __restrict__ masks,
        const unsigned* __restrict__ cmap, const unsigned* __restrict__ vincl,
        const unsigned* __restrict__ vflag, int* __restrict__ meta,
        int* __restrict__ kfinal) {
    __shared__ unsigned scan[1024];
    __shared__ u64 vkeptw[W64];
    __shared__ int sh_wlim;
    int t = threadIdx.x;
    if (t < W64) vkeptw[t] = 0ull;
    if (t == 0) sh_wlim = 0;
    __syncthreads();
    int total = meta[0];
    int nv = meta[3];

    if (t < 64) {  // ---- sweep wave ----
        int lane = t;
        int nblkv = (nv + 63) >> 6;
        u64 r0 = 0ull, r1 = 0ull;
        int nkv = 0, wl = 0;
        u64 diag_cur = (nblkv > 0) ? masks[(size_t)lane * W64] : 0ull;
        for (int w = 0; w < nblkv; ++w) {
            int base = w << 6;
            int rc = nv - base;
            u64 vm = (rc >= 64) ? ~0ull : ((1ull << rc) - 1ull);
            u64 rw = __shfl((w & 1) ? r1 : r0, w >> 1);
            u64 surv = ~rw & vm;
            int cend = (base + 63 < nv - 1) ? (base + 63) : (nv - 1);
            unsigned cm = cmap[cend];
            u64 diag_next = (w + 1 < nblkv)
                ? masks[(size_t)((w + 1) * 64 + lane) * W64 + (w + 1)] : 0ull;
            // in-block greedy chain (nonzero-diag candidates only)
            u64 Z = __ballot(diag_cur == 0ull);
            u64 rem = 0ull;
            u64 mnz = surv & ~Z;
            while (mnz) {
                int bb = __ffsll(mnz) - 1;
                mnz &= mnz - 1;
                if ((rem >> bb) & 1ull) continue;
                u64 db = __shfl(diag_cur, bb);
                rem |= db;
                mnz &= ~db;
            }
            u64 kept = surv & ~rem;
            int kp = __popcll(kept);
            // R-update: direct loads of kept rows, 4 independent rows in flight
            u64 km = kept, alo = 0ull, ahi = 0ull;
            while (km) {
                int b0 = __ffsll(km) - 1; km &= km - 1;
                const u64* p0 = masks + (size_t)(base + b0) * W64 + 2 * lane;
                u64 l0 = p0[0], h0 = p0[1];
                u64 l1 = 0, h1 = 0, l2 = 0, h2 = 0, l3 = 0, h3 = 0;
                if (km) { int b = __ffsll(km) - 1; km &= km - 1;
                    const u64* p = masks + (size_t)(base + b) * W64 + 2 * lane;
                    l1 = p[0]; h1 = p[1]; }
                if (km) { int b = __ffsll(km) - 1; km &= km - 1;
                    const u64* p = masks + (size_t)(base + b) * W64 + 2 * lane;
                    l2 = p[0]; h2 = p[1]; }
                if (km) { int b = __ffsll(km) - 1; km &= km - 1;
                    const u64* p = masks + (size_t)(base + b) * W64 + 2 * lane;
                    l3 = p[0]; h3 = p[1]; }
                alo |= l0 | l1 | l2 | l3;
                ahi |= h0 | h1 | h2 | h3;
            }
            r0 |= alo; r1 |= ahi;
            if (lane == 0) vkeptw[w] = kept;
            nkv += kp;
            wl = w + 1;
            if ((int)cm - cend + nkv >= MAXKEEP) break;  // merged kept reached cap
            diag_cur = diag_next;
        }
        if (lane == 0) sh_wlim = wl;
    }
    __syncthreads();
    int wlim = sh_wlim;

    // ---- finalize ----
    unsigned f[8];
    unsigned run = 0;
    #pragma unroll
    for (int e = 0; e < 8; ++e) {
        int s = t * 8 + e;
        unsigned kept = 0u;
        if (s < total) {
            if (!vflag[s]) kept = 1u;
            else {
                unsigned c = vincl[s] - 1u;
                int w = (int)(c >> 6);
                if (w < wlim && ((vkeptw[w] >> (c & 63u)) & 1ull)) kept = 1u;
            }
        }
        run += kept;
        f[e] = run;
    }
    scan[t] = run;
    __syncthreads();
    for (int o = 1; o < 1024; o <<= 1) {
        unsigned add = (t >= o) ? scan[t - o] : 0u;
        __syncthreads();
        scan[t] += add;
        __syncthreads();
    }
    unsigned excl = (t > 0) ? scan[t - 1] : 0u;
    #pragma unroll
    for (int e = 0; e < 8; ++e) {
        int s = t * 8 + e;
        unsigned kept = 0u;
        if (s < total) {
            if (!vflag[s]) kept = 1u;
            else {
                unsigned c = vincl[s] - 1u;
                int w = (int)(c >> 6);
                if (w < wlim && ((vkeptw[w] >> (c & 63u)) & 1ull)) kept = 1u;
            }
        }
        unsigned incl = excl + f[e];
        if (kept && incl <= (unsigned)MAXKEEP) kfinal[incl - 1] = s;
    }
    if (t == 1023) {
        unsigned tot = scan[1023];
        meta[2] = (int)(tot < (unsigned)MAXKEEP ? tot : (unsigned)MAXKEEP);
    }
}

// One wave per output row: butterfly argmax, strict-greater / lower-index
// tiebreak (== jnp.argmax first occurrence).
__global__ void __launch_bounds__(256) k_output(const float* __restrict__ in,
        const u64* __restrict__ gkeys, const int* __restrict__ meta,
        const int* __restrict__ kfinal, float* __restrict__ out) {
    int gw = (blockIdx.x * blockDim.x + threadIdx.x) >> 6;
    int lane = threadIdx.x & 63;
    if (gw >= MAXKEEP) return;
    int kc = meta[2];
    if (gw < kc) {
        int pos = kfinal[gw];
        u64 key = gkeys[pos];
        int bi = (int)(0xFFFFFFFFu - (unsigned)(key & 0xFFFFFFFFull));
        const float* row = in + (size_t)bi * NFEAT;
        float conf = row[4];
        float v0 = (lane < NCLS) ? conf * row[5 + lane] : -1.0f;
        float v1 = (lane < NCLS - 64) ? conf * row[5 + 64 + lane] : -1.0f;
        float bv = (v1 > v0) ? v1 : v0;
        int bix = (v1 > v0) ? (64 + lane) : lane;
        #pragma unroll
        for (int o = 1; o < 64; o <<= 1) {
            float ov = __shfl_xor(bv, o);
            int oi = __shfl_xor(bix, o);
            if (ov > bv || (ov == bv && oi < bix)) { bv = ov; bix = oi; }
        }
        float wv = 0.f;
        if (lane < 4) wv = row[lane];
        else if (lane == 4) wv = (float)bix;
        else wv = bv;
        if (lane < 6) out[gw * 6 + lane] = wv;
    } else {
        if (lane < 6) out[gw * 6 + lane] = 0.f;
    }
}

extern "C" void kernel_launch(void* const* d_in, const int* in_sizes, int n_in,
                              void* d_out, int out_size, void* d_ws, size_t ws_size,
                              hipStream_t stream) {
    const float* in = (const float*)d_in[0];
    float* out = (float*)d_out;
    char* ws = (char*)d_ws;
    // ws layout (bytes). masks OVERLAYS sort-phase scratch (all dead before k_masks).
    //   [0, 65536)           sorted   u64[8192]
    //   [65536, 65600)       meta     i32[16] {0:total,1:bstar,2:kc,3:nvalid}
    //   [65600, 69696)       kfinal   i32[1024]
    //   [69696, 102464)      vflag    u32[8192]
    //   [102464, 135232)     vincl    u32[8192]
    //   [135232, 168000)     cmap     u32[8192]
    //   [168000, 299072)     cboxes   float4[8192]
    //   [299072, 430144)     boxes4   float4[8192]
    //   [430144, 8818752)    masks    u64[8192*128] (8 MB), overlaying:
    //     [430144, 1630144)    scores   f32[300000]
    //     [1630144, 1892288)   hist16   u32[16*4096]
    //     [1892288, 1908672)   histsum  u32[4096]
    //     [1908672, 1925056)   cnt      u32[4096]
    //     [1925056, 1941440)   off      u32[4096]
    //     [1941440, 2006976)   unsorted u64[8192]
    u64* sorted = (u64*)(ws);
    int* meta = (int*)(ws + 65536);
    int* kfinal = (int*)(ws + 65600);
    unsigned* vflag = (unsigned*)(ws + 69696);
    unsigned* vincl = (unsigned*)(ws + 102464);
    unsigned* cmap = (unsigned*)(ws + 135232);
    float4* cboxes = (float4*)(ws + 168000);
    float4* boxes4 = (float4*)(ws + 299072);
    u64* masks = (u64*)(ws + 430144);
    float* scores = (float*)(ws + 430144);
    unsigned* hist16 = (unsigned*)(ws + 1630144);
    unsigned* histsum = (unsigned*)(ws + 1892288);
    unsigned* cnt = (unsigned*)(ws + 1908672);
    unsigned* off = (unsigned*)(ws + 1925056);
    u64* unsorted = (u64*)(ws + 1941440);

    k_init<<<dim3(256), dim3(256), 0, stream>>>(hist16, cnt, meta);
    k_scores<<<dim3((NBOX + SC_ROWS - 1) / SC_ROWS), dim3(256), 0, stream>>>(in, scores, hist16);
    k_thresh<<<dim3(1), dim3(1024), 0, stream>>>(hist16, histsum, off, meta);
    k_scatter<<<dim3((NBOX + 255) / 256), dim3(256), 0, stream>>>(scores, meta, off, cnt, unsorted);
    k_rank<<<dim3(CMAX / 256), dim3(256), 0, stream>>>(in, unsorted, off, histsum, meta, sorted, boxes4, vflag);
    k_vscan<<<dim3(1), dim3(1024), 0, stream>>>(vflag, boxes4, meta, vincl, cmap, cboxes);
    k_masks<<<dim3(W64, W64), dim3(256), 0, stream>>>(cboxes, meta, masks);
    k_sweepfin<<<dim3(1), dim3(1024), 0, stream>>>(masks, cmap, vincl, vflag, meta, kfinal);
    k_output<<<dim3((MAXKEEP * 64 + 255) / 256), dim3(256), 0, stream>>>(in, sorted, meta, kfinal, out);
}